// Round 4
// baseline (4375.252 us; speedup 1.0000x reference)
//
#include <hip/hip_runtime.h>
#include <math.h>

#define H 64
#define SEQ_T 1024
#define BATCH 512
#define NTHR 256            // 4 waves: thread = (j = 16*wv + jl, ks = lane>>4)
#define NBLK BATCH          // 1 block = 1 batch row; 512 blocks = 2 blocks/CU

__device__ __forceinline__ float sigmoid_f(float v) {
    return 1.0f / (1.0f + __expf(-v));
}

// overflow-safe tanh: exp overflow -> inf -> 2/inf = 0 -> t=1
__device__ __forceinline__ float tanh_f(float v) {
    float ax = fabsf(v);
    float e = __expf(2.0f * ax);
    float t = 1.0f - 2.0f / (e + 1.0f);
    return copysignf(t, v);
}

// Empty asm with "+v" per component: zero runtime instructions, but forces the
// value to live in an arch VGPR here and blocks rematerialization/AGPR-shelving.
#define PIN4(v) asm volatile("" : "+v"((v).x), "+v"((v).y), "+v"((v).z), "+v"((v).w))

// 24 FMAs: one 4-wide k-chunk of both matmuls, all 3 gates
#define FMA_BOTH(xv, hv, q)                                                     \
    ar = fmaf((xv).x, wIv[0][q].x, ar); ar = fmaf((xv).y, wIv[0][q].y, ar);     \
    ar = fmaf((xv).z, wIv[0][q].z, ar); ar = fmaf((xv).w, wIv[0][q].w, ar);     \
    az = fmaf((xv).x, wIv[1][q].x, az); az = fmaf((xv).y, wIv[1][q].y, az);     \
    az = fmaf((xv).z, wIv[1][q].z, az); az = fmaf((xv).w, wIv[1][q].w, az);     \
    an = fmaf((xv).x, wIv[2][q].x, an); an = fmaf((xv).y, wIv[2][q].y, an);     \
    an = fmaf((xv).z, wIv[2][q].z, an); an = fmaf((xv).w, wIv[2][q].w, an);     \
    hr = fmaf((hv).x, wHv[0][q].x, hr); hr = fmaf((hv).y, wHv[0][q].y, hr);     \
    hr = fmaf((hv).z, wHv[0][q].z, hr); hr = fmaf((hv).w, wHv[0][q].w, hr);     \
    hz = fmaf((hv).x, wHv[1][q].x, hz); hz = fmaf((hv).y, wHv[1][q].y, hz);     \
    hz = fmaf((hv).z, wHv[1][q].z, hz); hz = fmaf((hv).w, wHv[1][q].w, hz);     \
    hn = fmaf((hv).x, wHv[2][q].x, hn); hn = fmaf((hv).y, wHv[2][q].y, hn);     \
    hn = fmaf((hv).z, wHv[2][q].z, hn); hn = fmaf((hv).w, wHv[2][q].w, hn);

// One GRU timestep. PR/PW are compile-time LDS buffer indices (immediate
// ds offsets). XC* = current x regs, XN* = prefetch target regs.
#define GRU_STEP(XC0, XC1, XC2, XC3, XN0, XN1, XN2, XN3, PR, PW, DO_PF)         \
  {                                                                             \
    /* prefetch next timestep's x (off the serial chain) */                     \
    if (layer == 0) {                                                           \
        if ((DO_PF) && ks == 0) {                                               \
            XN0 = make_float4(pX[0], pX[1], pX[2], pX[3]);                      \
            XN1.x = pX[4];                                                      \
        }                                                                       \
        pX += 5;                                                                \
    } else {                                                                    \
        if (DO_PF) { XN0 = pA[0]; XN1 = pA[1]; XN2 = pA[2]; XN3 = pA[3]; }      \
        pA += H / 4;                                                            \
    }                                                                           \
    float4 h0 = *(const float4*)(&hbuf[PR][k0]);                                \
    float4 h1 = *(const float4*)(&hbuf[PR][k0 + 4]);                            \
    float4 h2 = *(const float4*)(&hbuf[PR][k0 + 8]);                            \
    float4 h3 = *(const float4*)(&hbuf[PR][k0 + 12]);                           \
    float ar = 0.f, az = 0.f, an = 0.f, hr = 0.f, hz = 0.f, hn = 0.f;           \
    FMA_BOTH(XC0, h0, 0)                                                        \
    FMA_BOTH(XC1, h1, 1)                                                        \
    FMA_BOTH(XC2, h2, 2)                                                        \
    FMA_BOTH(XC3, h3, 3)                                                        \
    float sR = ar + hr, sZ = az + hz, sN = an, sH = hn;                         \
    sR += __shfl_xor(sR, 16, 64); sR += __shfl_xor(sR, 32, 64);                 \
    sZ += __shfl_xor(sZ, 16, 64); sZ += __shfl_xor(sZ, 32, 64);                 \
    sN += __shfl_xor(sN, 16, 64); sN += __shfl_xor(sN, 32, 64);                 \
    sH += __shfl_xor(sH, 16, 64); sH += __shfl_xor(sH, 32, 64);                 \
    float r = sigmoid_f(sR + bR);                                               \
    float z = sigmoid_f(sZ + bZ);                                               \
    float n = tanh_f(sN + bNi + r * (sH + bNh));                                \
    float hnew = fmaf(z, hprev - n, n); /* (1-z)*n + z*h */                     \
    hprev = hnew;                                                               \
    if (ks == 0) {                                                              \
        hbuf[PW][j] = hnew;                                                     \
        if (layer < 4) *pSt = hnew;                                             \
    }                                                                           \
    pSt += H;                                                                   \
    __syncthreads();                                                            \
  }

__global__ __launch_bounds__(NTHR, 2) void gru_all_kernel(
    const float* __restrict__ x,
    const float* __restrict__ w_ih0, const float* __restrict__ w_hh0,
    const float* __restrict__ b_ih0, const float* __restrict__ b_hh0,
    const float* __restrict__ w_ih, const float* __restrict__ w_hh,
    const float* __restrict__ b_ih, const float* __restrict__ b_hh,
    const float* __restrict__ w_fc, const float* __restrict__ b_fc,
    float* __restrict__ out, float* __restrict__ act)
{
    __shared__ __align__(16) float hbuf[2][H];  // double-buffered hidden state
    __shared__ float partial[4];

    const int tid  = threadIdx.x;
    const int wv   = tid >> 6;        // wave 0..3
    const int lane = tid & 63;
    const int jl   = lane & 15;
    const int ks   = lane >> 4;       // k-slice 0..3 (k in [16ks, 16ks+16))
    const int j    = wv * 16 + jl;    // output h-index
    const int k0   = ks * 16;
    const int b    = blockIdx.x;

    float* __restrict__ actb = act + (size_t)b * (SEQ_T * H);
    const float* __restrict__ xb = x + (size_t)b * (SEQ_T * 5);

    float hprev = 0.0f;

    for (int layer = 0; layer < 5; ++layer) {
        // ---- weight slices -> VGPRs (reused 1024x) ----
        float4 wIv[3][4], wHv[3][4];
        {
            const float* whp = (layer == 0) ? w_hh0 : w_hh + (size_t)(layer - 1) * (192 * H);
            #pragma unroll
            for (int g = 0; g < 3; ++g) {
                const float4* row = (const float4*)(whp + (g * 64 + j) * H + k0);
                #pragma unroll
                for (int q = 0; q < 4; ++q) wHv[g][q] = row[q];
            }
            if (layer == 0) {
                // input dim = 5: only ks==0 lanes hold nonzero weights
                #pragma unroll
                for (int g = 0; g < 3; ++g)
                    #pragma unroll
                    for (int q = 0; q < 4; ++q) wIv[g][q] = make_float4(0.f, 0.f, 0.f, 0.f);
                if (ks == 0) {
                    #pragma unroll
                    for (int g = 0; g < 3; ++g) {
                        const float* row = w_ih0 + (g * 64 + j) * 5;
                        wIv[g][0] = make_float4(row[0], row[1], row[2], row[3]);
                        wIv[g][1].x = row[4];
                    }
                }
            } else {
                const float* wip = w_ih + (size_t)(layer - 1) * (192 * H);
                #pragma unroll
                for (int g = 0; g < 3; ++g) {
                    const float4* row = (const float4*)(wip + (g * 64 + j) * H + k0);
                    #pragma unroll
                    for (int q = 0; q < 4; ++q) wIv[g][q] = row[q];
                }
            }
        }

        // biases (r/z input+hidden pre-summed; n-gate parts stay separate)
        float bR, bZ, bNi, bNh;
        {
            const float* bip = (layer == 0) ? b_ih0 : b_ih + (layer - 1) * 192;
            const float* bhp = (layer == 0) ? b_hh0 : b_hh + (layer - 1) * 192;
            bR  = bip[j] + bhp[j];
            bZ  = bip[j + 64] + bhp[j + 64];
            bNi = bip[j + 128];
            bNh = bhp[j + 128];
        }

        hprev = 0.0f;
        if (ks == 0) hbuf[0][j] = 0.0f;

        // named x double-buffer regs, zeroed ONCE (layer-0 ks!=0 lanes stay 0)
        float4 xA0, xA1, xA2, xA3, xB0, xB1, xB2, xB3;
        xA0 = xA1 = xA2 = xA3 = make_float4(0.f, 0.f, 0.f, 0.f);
        xB0 = xB1 = xB2 = xB3 = xA0;

        // moving pointers (bump instead of per-step mul)
        const float*  pX  = xb;                          // layer 0 input, t=0
        const float4* pA  = (const float4*)(actb + k0);  // layers>=1 act,  t=0
        float*        pSt = actb + j;                    // store ptr,      t=0

        // prologue: load t=0 into A buffers
        if (layer == 0) {
            if (ks == 0) { xA0 = make_float4(pX[0], pX[1], pX[2], pX[3]); xA1.x = pX[4]; }
            pX += 5;
        } else {
            xA0 = pA[0]; xA1 = pA[1]; xA2 = pA[2]; xA3 = pA[3];
            pA += H / 4;
        }
        __syncthreads();  // hbuf[0] zeroed, prev layer's act writes drained

        for (int t = 0; t < SEQ_T; t += 2) {
            // re-pin weights every iteration: keeps them ArchVGPR-resident
            #pragma unroll
            for (int g = 0; g < 3; ++g) {
                #pragma unroll
                for (int q = 0; q < 4; ++q) { PIN4(wIv[g][q]); PIN4(wHv[g][q]); }
            }
            GRU_STEP(xA0, xA1, xA2, xA3, xB0, xB1, xB2, xB3, 0, 1, true)
            GRU_STEP(xB0, xB1, xB2, xB3, xA0, xA1, xA2, xA3, 1, 0, (t + 2 < SEQ_T))
        }
    }

    // ---- fused FC on last timestep: out[b] = h . w_fc + b_fc ----
    float v = (ks == 0) ? hprev * w_fc[j] : 0.0f;
    v += __shfl_xor(v, 1, 64);
    v += __shfl_xor(v, 2, 64);
    v += __shfl_xor(v, 4, 64);
    v += __shfl_xor(v, 8, 64);
    if (lane == 0) partial[wv] = v;
    __syncthreads();
    if (tid == 0) out[b] = partial[0] + partial[1] + partial[2] + partial[3] + b_fc[0];
}

extern "C" void kernel_launch(void* const* d_in, const int* in_sizes, int n_in,
                              void* d_out, int out_size, void* d_ws, size_t ws_size,
                              hipStream_t stream) {
    const float* x     = (const float*)d_in[0];
    const float* w_ih0 = (const float*)d_in[1];
    const float* w_hh0 = (const float*)d_in[2];
    const float* b_ih0 = (const float*)d_in[3];
    const float* b_hh0 = (const float*)d_in[4];
    const float* w_ih  = (const float*)d_in[5];
    const float* w_hh  = (const float*)d_in[6];
    const float* b_ih  = (const float*)d_in[7];
    const float* b_hh  = (const float*)d_in[8];
    const float* w_fc  = (const float*)d_in[9];
    const float* b_fc  = (const float*)d_in[10];
    float* out = (float*)d_out;
    float* act = (float*)d_ws;  // [BATCH][SEQ_T][H] fp32 = 128 MiB

    hipLaunchKernelGGL(gru_all_kernel, dim3(NBLK), dim3(NTHR), 0, stream,
                       x, w_ih0, w_hh0, b_ih0, b_hh0,
                       w_ih, w_hh, b_ih, b_hh, w_fc, b_fc, out, act);
}